// Round 1
// baseline (4159.216 us; speedup 1.0000x reference)
//
#include <hip/hip_runtime.h>
#include <hip/hip_fp16.h>

#define B_ 512
#define T_ 256
#define H_ 1024
#define G4_ 4096

typedef _Float16 half8 __attribute__((ext_vector_type(8)));
typedef float f32x4 __attribute__((ext_vector_type(4)));

__device__ __forceinline__ float fast_sigmoid(float x) {
    return 1.0f / (1.0f + __expf(-x));
}
__device__ __forceinline__ float fast_tanh(float x) {
    float x2 = fminf(fmaxf(2.0f * x, -30.0f), 30.0f);
    float e = __expf(x2);
    return (e - 1.0f) / (e + 1.0f);
}

// Repack W_hh [4096 x 1024] fp32 -> fp16 in MFMA B-fragment order:
// Wp[((j*32 + ki)*4 + nt)*64*8 + l*8 + e] = W_hh[gc][k]
//   gc = nt*1024 + j*16 + (l&15),  k = ki*32 + (l>>4)*8 + e
__global__ void pack_w(const float* __restrict__ Whh, _Float16* __restrict__ Wp) {
    int idx = blockIdx.x * blockDim.x + threadIdx.x;   // over 4096*1024
    int gc = idx >> 10, k = idx & 1023;
    int nt = gc >> 10, khid = gc & 1023;
    int j = khid >> 4, lk = khid & 15;
    int ki = k >> 5, hi = (k >> 3) & 3, e = k & 7;
    int l = hi * 16 + lk;
    Wp[(((((j * 32 + ki) * 4 + nt) * 64) + l) << 3) + e] = (_Float16)Whh[idx];
}

__global__ void init_misc(const float* __restrict__ bih, const float* __restrict__ bhh,
                          const float* __restrict__ bout,
                          float* __restrict__ bias, float* __restrict__ out) {
    int idx = blockIdx.x * blockDim.x + threadIdx.x;   // 512*256 = 131072 threads
    if (idx < G4_) bias[idx] = bih[idx] + bhh[idx];
    if (idx < B_ * T_) out[idx] = bout[0];
}

// One timestep. Grid 256 WGs x 512 threads.
// WG -> (batch tile i of 128 rows, hidden tile j of 16 units -> 64 gate cols).
// Wave w owns 16 batch rows; its 4 acc frags are the 4 gate types (i,f,g,o)
// for those rows x 16 hidden units -> elementwise update fully in-register.
// h stored fp16 as [kb=k/8][b][e=k%8] so A-fragments are direct 16B loads.
__global__ __launch_bounds__(512, 1)
void lstm_step(const _Float16* __restrict__ Wp,
               const float* __restrict__ bias,
               const float* __restrict__ x,
               const float* __restrict__ Wih,
               const float* __restrict__ Wout,
               const _Float16* __restrict__ hprev,
               _Float16* __restrict__ hnext,
               float* __restrict__ c,
               float* __restrict__ out,
               int t) {
    const int blk = blockIdx.x;
    // XCD-locality mapping: all 4 batch-tiles of a given j land on the same XCD
    const int j = (blk & 7) * 8 + ((blk >> 3) & 7);   // hidden tile [0,64)
    const int i = blk >> 6;                            // batch tile [0,4)
    const int tid = threadIdx.x;
    const int w = tid >> 6, l = tid & 63;
    const int lk = l & 15, hi = l >> 4;

    const int rowbase = i * 128 + w * 16;   // 16 batch rows for this wave
    const int khid = j * 16 + lk;           // hidden unit for this lane (cols)

    f32x4 acc[4];
    // init accumulators with bias + x_t * W_ih  (D-layout: row = hi*4+r, col = lk)
    float xv[4];
#pragma unroll
    for (int r = 0; r < 4; ++r) xv[r] = x[(rowbase + hi * 4 + r) * T_ + t];
#pragma unroll
    for (int nt = 0; nt < 4; ++nt) {
        int gc = nt * 1024 + khid;
        float bz = bias[gc], wi = Wih[gc];
#pragma unroll
        for (int r = 0; r < 4; ++r) acc[nt][r] = bz + xv[r] * wi;
    }

    const _Float16* Aptr = hprev + ((size_t)(hi * 512) + rowbase + lk) * 8;
    const _Float16* Bptr = Wp + ((size_t)(j * 32) * 4 * 64 + l) * 8;

#pragma unroll 4
    for (int ki = 0; ki < 32; ++ki) {
        half8 a = *(const half8*)(Aptr + (size_t)ki * 4 * 512 * 8);
        const _Float16* bp = Bptr + (size_t)ki * 4 * 64 * 8;
#pragma unroll
        for (int nt = 0; nt < 4; ++nt) {
            half8 b = *(const half8*)(bp + (size_t)nt * 64 * 8);
            acc[nt] = __builtin_amdgcn_mfma_f32_16x16x32_f16(a, b, acc[nt], 0, 0, 0);
        }
    }

    // Elementwise LSTM update. acc[0..3] = i,f,g,o pre-activations.
    float p[4];
#pragma unroll
    for (int r = 0; r < 4; ++r) {
        float iv = fast_sigmoid(acc[0][r]);
        float fv = fast_sigmoid(acc[1][r]);
        float gv = fast_tanh(acc[2][r]);
        float ov = fast_sigmoid(acc[3][r]);
        int cidx = ((blk * 8 + w) * 64 + l) * 4 + r;
        float cv = fv * c[cidx] + iv * gv;
        c[cidx] = cv;
        float hv = ov * fast_tanh(cv);
        int brow = rowbase + hi * 4 + r;
        hnext[(((size_t)(khid >> 3) * 512 + brow) << 3) + (khid & 7)] = (_Float16)hv;
        p[r] = hv * Wout[khid];
    }
    // reduce output partials across the 16 lanes (lk) sharing the same rows
#pragma unroll
    for (int mask = 1; mask <= 8; mask <<= 1) {
#pragma unroll
        for (int r = 0; r < 4; ++r) p[r] += __shfl_xor(p[r], mask);
    }
    if (lk == 0) {
#pragma unroll
        for (int r = 0; r < 4; ++r)
            atomicAdd(&out[(rowbase + hi * 4 + r) * T_ + t], p[r]);
    }
}

extern "C" void kernel_launch(void* const* d_in, const int* in_sizes, int n_in,
                              void* d_out, int out_size, void* d_ws, size_t ws_size,
                              hipStream_t stream) {
    const float* x    = (const float*)d_in[0];
    const float* Wih  = (const float*)d_in[1];
    const float* Whh  = (const float*)d_in[2];
    const float* bih  = (const float*)d_in[3];
    const float* bhh  = (const float*)d_in[4];
    const float* Wout = (const float*)d_in[5];
    const float* bout = (const float*)d_in[6];
    float* out = (float*)d_out;

    char* ws = (char*)d_ws;
    _Float16* Wp = (_Float16*)ws;                         // 8 MB packed W_hh
    _Float16* hA = (_Float16*)(ws + (8 << 20));           // 1 MB h ping
    _Float16* hB = (_Float16*)(ws + (9 << 20));           // 1 MB h pong
    float* c     = (float*)(ws + (10 << 20));             // 2 MB cell state
    float* bias  = (float*)(ws + (12 << 20));             // 16 KB

    // zero h (both buffers) and c: bytes [8MB, 12MB)
    hipMemsetAsync(ws + (8 << 20), 0, 4 << 20, stream);

    pack_w<<<(G4_ * H_) / 256, 256, 0, stream>>>(Whh, Wp);
    init_misc<<<512, 256, 0, stream>>>(bih, bhh, bout, bias, out);

    _Float16* hbuf[2] = { hA, hB };
    for (int t = 0; t < T_; ++t) {
        lstm_step<<<256, 512, 0, stream>>>(Wp, bias, x, Wih, Wout,
                                           hbuf[t & 1], hbuf[(t & 1) ^ 1],
                                           c, out, t);
    }
}